// Round 1
// baseline (147.507 us; speedup 1.0000x reference)
//
#include <hip/hip_runtime.h>

#define T_LEN 2048
#define NSTATE 64
#define NCHUNK 16
#define CH_S 128      // stored steps per chunk
#define WARM 64       // warm-up steps (10.7*mu) before the stored region
#define RK 16         // renorm every 16 steps (scale cancels in LLR)

// v_add_f32 with DPP-modified src: single VALU instr, no DS op.
template<int CTRL>
__device__ __forceinline__ float dpp_add(float v) {
    int r = __builtin_amdgcn_update_dpp(0, __float_as_int(v), CTRL, 0xF, 0xF, true);
    return v + __int_as_float(r);
}

// Full 64-lane sum, result in every lane.
// Levels 1,2 = quad_perm xor; 4,8 = row_ror (rotate is fine for a sum);
// only the 16/32 crossings need a shuffle.
__device__ __forceinline__ float wave_sum64(float v) {
    v = dpp_add<0xB1>(v);    // quad_perm [1,0,3,2]  (xor 1)
    v = dpp_add<0x4E>(v);    // quad_perm [2,3,0,1]  (xor 2)
    v = dpp_add<0x124>(v);   // row_ror:4
    v = dpp_add<0x128>(v);   // row_ror:8  -> full row-of-16 sum in each lane
    v += __shfl_xor(v, 16, 64);
    v += __shfl_xor(v, 32, 64);
    return v;
}

// v + v[lane^1] via DPP quad_perm [1,0,3,2] — VALU pipe, no DS op.
__device__ __forceinline__ float pair_sum_xor1(float v) {
    int r = __builtin_amdgcn_update_dpp(0, __float_as_int(v), 0xB1, 0xF, 0xF, true);
    return v + __int_as_float(r);
}

// cheap fp32 -> bf16 (round-half-up): 2 VALU ops
__device__ __forceinline__ unsigned short bf16_of(float f) {
    return (unsigned short)((__float_as_uint(f) + 0x8000u) >> 16);
}

// GEN_POLY = ('1111001','1011011'), mu=6, NS=64.
// State s: shift register, most-recent bit = MSB (bit 5).
// o0 parity mask of s: 57 ; o1 mask: 27.
// log2-domain branch metric: x_s = kE*la + (kE*c0)*l0 + (kE*c1)*l1, kE = 0.5*log2(e)
// gamma(s,0) = 2^x_s ; gamma(s,1) = 2^-x_s.
// to(s,b) = (b<<5) | (s>>1).

// ---------------- Kernel F: forward sweep, writes alpha_t (bf16) ----------------
// Identical math to the proven combined-sweep dir==0 branch.
__global__ __launch_bounds__(256, 4)
void bcjr_fwd_kernel(const float* __restrict__ llr_ch,   // [B][2*T]
                     const float* __restrict__ llr_a,    // [B][T]
                     unsigned short* __restrict__ wsA)   // [B][T][64] bf16 alpha_t
{
    const int wave  = blockIdx.x * 4 + (threadIdx.x >> 6);
    const int lane  = threadIdx.x & 63;
    const int chunk = wave & (NCHUNK - 1);
    const int b     = wave >> 4;

    const float c0 = 1.0f - 2.0f * (float)(__popc(lane & 57) & 1);
    const float c1 = 1.0f - 2.0f * (float)(__popc(lane & 27) & 1);
    const float kE = 0.5f * 1.442695040888963f;
    const float k0 = kE * c0, k1 = kE * c1;

    const float* chp = llr_ch + (size_t)b * (2 * T_LEN);
    const float* lap = llr_a  + (size_t)b * T_LEN;
    unsigned short* w = wsA + (size_t)b * T_LEN * NSTATE;

    const int  fs0 = 2 * (lane & 31);
    const bool fhi = (lane >= 32);
    const int t0 = chunk * CH_S;
    const int ts = (chunk == 0) ? t0 : t0 - WARM;
    float state = (chunk == 0) ? ((lane == 0) ? 1.0f : 0.0f) : (1.0f / 64.0f);

    for (int g = ts; g < t0 + CH_S; g += RK) {
        const bool store = (g >= t0);
        #pragma unroll
        for (int h = 0; h < 2; ++h) {
            const int gb = g + 8 * h;
            const float4* c4 = (const float4*)(chp + 2 * gb);
            const float4* a4 = (const float4*)(lap + gb);
            float4 cc[4], aa[2];
            #pragma unroll
            for (int i = 0; i < 4; ++i) cc[i] = c4[i];
            #pragma unroll
            for (int i = 0; i < 2; ++i) aa[i] = a4[i];
            unsigned short* wb = w + (size_t)gb * NSTATE + lane;
            #pragma unroll
            for (int i = 0; i < 8; ++i) {
                float l0 = (i & 1) ? cc[i >> 1].z : cc[i >> 1].x;
                float l1 = (i & 1) ? cc[i >> 1].w : cc[i >> 1].y;
                float la = ((const float*)aa)[i];
                if (store) wb[i * NSTATE] = bf16_of(state);   // alpha_t
                float x   = fmaf(la, kE, fmaf(l0, k0, l1 * k1));
                float g0v = exp2f(x);
                float g1v = __builtin_amdgcn_rcpf(g0v);
                float s0  = pair_sum_xor1(state * g0v);
                float s1  = pair_sum_xor1(state * g1v);
                float a0  = __shfl(s0, fs0, 64);
                float a1  = __shfl(s1, fs0, 64);
                state = fhi ? a1 : a0;
            }
        }
        float s = wave_sum64(state);
        state = state * __builtin_amdgcn_rcpf(s);
    }
}

// ---------------- Kernel G: backward sweep + fused LLR ----------------
// beta stays in registers (fp32, never stored). Per stored step:
//   p0 = gamma(s,0)*beta_next[to0(s)], p1 = gamma(s,1)*beta_next[to1(s)]
//   llr_t = ln(sum_s alpha_t[s]*p0) - ln(sum_s alpha_t[s]*p1)
// Dual reduction: fold lanes i<->i+32 for both sums, select n0-partials into
// the low half and n1-partials into the high half, one shared 5-level
// butterfly (4 DPP-fused adds + 1 xor16 shuffle), one v_log, one xor32.
__global__ __launch_bounds__(256, 4)
void bcjr_bwd_llr_kernel(const float* __restrict__ llr_ch,
                         const float* __restrict__ llr_a,
                         const unsigned short* __restrict__ wsA,
                         float* __restrict__ out)          // [B][T]
{
    const int wave  = blockIdx.x * 4 + (threadIdx.x >> 6);
    const int lane  = threadIdx.x & 63;
    const int chunk = wave & (NCHUNK - 1);
    const int b     = wave >> 4;

    const float c0 = 1.0f - 2.0f * (float)(__popc(lane & 57) & 1);
    const float c1 = 1.0f - 2.0f * (float)(__popc(lane & 27) & 1);
    const float kE = 0.5f * 1.442695040888963f;
    const float k0 = kE * c0, k1 = kE * c1;

    const float* chp = llr_ch + (size_t)b * (2 * T_LEN);
    const float* lap = llr_a  + (size_t)b * T_LEN;
    const unsigned short* wa = wsA + (size_t)b * T_LEN * NSTATE;
    float* outp = out + (size_t)b * T_LEN;

    const int  bs0 = lane >> 1;          // to0(s) = s>>1
    const int  bs1 = 32 + (lane >> 1);   // to1(s) = 32 + (s>>1)
    const bool fhi = (lane >= 32);
    const int t0 = chunk * CH_S;
    const int te = (chunk == NCHUNK - 1) ? (t0 + CH_S) : (t0 + CH_S + WARM);
    float state = 1.0f / 64.0f;          // beta_T = 1/NS exactly for last chunk

    for (int g = te - RK; g >= t0; g -= RK) {
        const bool act = (g < t0 + CH_S);   // stored region: compute LLR
        #pragma unroll
        for (int h = 1; h >= 0; --h) {
            const int gb = g + 8 * h;
            const float4* c4 = (const float4*)(chp + 2 * gb);
            const float4* a4 = (const float4*)(lap + gb);
            float4 cc[4], aa[2];
            #pragma unroll
            for (int i = 0; i < 4; ++i) cc[i] = c4[i];
            #pragma unroll
            for (int i = 0; i < 2; ++i) aa[i] = a4[i];
            float av[8];
            if (act) {
                // alpha_t for the 8 steps: 128 B coalesced ushort loads, issued early
                const unsigned short* ap = wa + (size_t)gb * NSTATE + lane;
                #pragma unroll
                for (int i = 0; i < 8; ++i)
                    av[i] = __uint_as_float(((unsigned)ap[i * NSTATE]) << 16);
            }
            #pragma unroll
            for (int i = 7; i >= 0; --i) {
                float l0 = (i & 1) ? cc[i >> 1].z : cc[i >> 1].x;
                float l1 = (i & 1) ? cc[i >> 1].w : cc[i >> 1].y;
                float la = ((const float*)aa)[i];
                float x   = fmaf(la, kE, fmaf(l0, k0, l1 * k1));
                float g0v = exp2f(x);
                float g1v = __builtin_amdgcn_rcpf(g0v);
                float t0v = __shfl(state, bs0, 64);
                float t1v = __shfl(state, bs1, 64);
                float p0 = g0v * t0v;
                float p1 = g1v * t1v;
                if (act) {
                    float na = av[i] * p0;                 // n0 contribution of state s
                    float nb = av[i] * p1;                 // n1 contribution
                    na += __shfl_xor(na, 32, 64);          // fold 32: pairs complete
                    nb += __shfl_xor(nb, 32, 64);
                    float z = fhi ? nb : na;               // lo half: n0, hi half: n1
                    z = dpp_add<0xB1>(z);                  // xor1 (quad_perm)
                    z = dpp_add<0x4E>(z);                  // xor2 (quad_perm)
                    z = dpp_add<0x124>(z);                 // row_ror:4
                    z = dpp_add<0x128>(z);                 // row_ror:8
                    z += __shfl_xor(z, 16, 64);            // lanes 0-31: n0, 32-63: n1
                    float lg = __log2f(z);
                    float d  = (lg - __shfl_xor(lg, 32, 64)) * 0.6931471805599453f;
                    if (lane == 0) outp[gb + i] = d;       // llr_t
                }
                state = p0 + p1;                           // beta_t
            }
        }
        float s = wave_sum64(state);
        state = state * __builtin_amdgcn_rcpf(s);
    }
}

extern "C" void kernel_launch(void* const* d_in, const int* in_sizes, int n_in,
                              void* d_out, int out_size, void* d_ws, size_t ws_size,
                              hipStream_t stream) {
    const float* llr_ch = (const float*)d_in[0];
    const float* llr_a  = (const float*)d_in[1];
    float* out = (float*)d_out;

    int B = in_sizes[0] / (2 * T_LEN);   // 256
    unsigned short* wsA = (unsigned short*)d_ws;  // [B][T][64] bf16, 64 MiB

    int n_waves = B * NCHUNK;            // 4096 waves per phase
    hipLaunchKernelGGL(bcjr_fwd_kernel, dim3(n_waves / 4), dim3(256), 0, stream,
                       llr_ch, llr_a, wsA);
    hipLaunchKernelGGL(bcjr_bwd_llr_kernel, dim3(n_waves / 4), dim3(256), 0, stream,
                       llr_ch, llr_a, wsA, out);
}